// Round 1
// 904.489 us; speedup vs baseline: 1.0064x; 1.0064x over previous
//
#include <hip/hip_runtime.h>

// Problem constants (from reference): V=2048, G=48, K=128, B=1024
#define V 2048
#define G 48
#define K 128
#define B 1024

// Workspace layout (ints): [0, B) word_idx[b]

// One block (256 threads) per batch row: find the 1.0 in the one-hot input.
// Exactly one thread finds it -> no reduction needed.
__global__ void find_word_idx(const float* __restrict__ input,
                              int* __restrict__ word_idx) {
    int b = blockIdx.x;
    int t = threadIdx.x;
    const float* row = input + (size_t)b * V;
    int base = t * 8;  // 256 threads * 8 floats = 2048
    float4 x0 = *(const float4*)(row + base);
    float4 x1 = *(const float4*)(row + base + 4);
    int hit = -1;
    if      (x0.x > 0.5f) hit = base + 0;
    else if (x0.y > 0.5f) hit = base + 1;
    else if (x0.z > 0.5f) hit = base + 2;
    else if (x0.w > 0.5f) hit = base + 3;
    else if (x1.x > 0.5f) hit = base + 4;
    else if (x1.y > 0.5f) hit = base + 5;
    else if (x1.z > 0.5f) hit = base + 6;
    else if (x1.w > 0.5f) hit = base + 7;
    if (hit >= 0) word_idx[b] = hit;
}

// One wave (64 lanes) per (g, b) pair.
// Two-phase scan of perms[g, word_idx[b], :]:
//   phase 1: issue 4 independent 1KB chunk loads (first 4KB of the row),
//            evaluate all 16 elems/lane in VALU, ONE ballot for the half.
//   phase 2 (50% of waves): same for the back 4KB.
// This replaces the old per-1KB load->ballot->branch serial chain
// (avg ~4.5 dependent HBM round trips) with <=2 latency rounds and
// 4KB in flight per wave (32MB aggregate -> BW-saturating).
// g-major wave ordering keeps duplicate-word rows within a g temporally
// close for L2/L3 reuse (touched perms footprint ~300 MB, prefix-reads
// mostly L3-resident across duplicates).
__global__ void scan_and_gather(const float* __restrict__ perms,
                                const float* __restrict__ emb,
                                const int* __restrict__ word_idx,
                                float* __restrict__ out) {
    int wid  = blockIdx.x * 4 + (threadIdx.x >> 6);  // 4 waves per 256-thread block
    int lane = threadIdx.x & 63;
    int g = wid >> 10;        // / B
    int b = wid & (B - 1);    // % B
    int w = word_idx[b];
    const float* row = perms + ((size_t)g * V + (size_t)w) * V;

    auto check = [](float4 x, int base) -> int {
        int h = -1;
        if      (x.x > 0.5f) h = base + 0;
        else if (x.y > 0.5f) h = base + 1;
        else if (x.z > 0.5f) h = base + 2;
        else if (x.w > 0.5f) h = base + 3;
        return h;
    };

    int idx;
    {
        // Phase 1: front half of the row, 4 independent loads issued together.
        int off = lane * 4;
        float4 c0 = *(const float4*)(row + off);
        float4 c1 = *(const float4*)(row + off + 256);
        float4 c2 = *(const float4*)(row + off + 512);
        float4 c3 = *(const float4*)(row + off + 768);
        int h = check(c0, off);
        if (h < 0) h = check(c1, off + 256);
        if (h < 0) h = check(c2, off + 512);
        if (h < 0) h = check(c3, off + 768);
        unsigned long long m = __ballot(h >= 0);
        if (m) {
            idx = __shfl(h, (int)__builtin_ctzll(m));
        } else {
            // Phase 2: back half.
            float4 d0 = *(const float4*)(row + off + 1024);
            float4 d1 = *(const float4*)(row + off + 1280);
            float4 d2 = *(const float4*)(row + off + 1536);
            float4 d3 = *(const float4*)(row + off + 1792);
            h = check(d0, off + 1024);
            if (h < 0) h = check(d1, off + 1280);
            if (h < 0) h = check(d2, off + 1536);
            if (h < 0) h = check(d3, off + 1792);
            m = __ballot(h >= 0);
            idx = __shfl(h, (int)__builtin_ctzll(m));
        }
    }

    // Fused embedding gather: 64 lanes * float2 = 128 floats = one emb row.
    // emb is 1MB -> L2-resident after first touches.
    float2 e = *(const float2*)(emb + (size_t)idx * K + lane * 2);
    *(float2*)(out + ((size_t)b * G + g) * K + lane * 2) = e;
}

extern "C" void kernel_launch(void* const* d_in, const int* in_sizes, int n_in,
                              void* d_out, int out_size, void* d_ws, size_t ws_size,
                              hipStream_t stream) {
    const float* input = (const float*)d_in[0];  // [B, V]
    const float* perms = (const float*)d_in[1];  // [G, V, V]
    const float* emb   = (const float*)d_in[2];  // [V, K]
    float* out = (float*)d_out;                  // [B, G, K]

    int* word_idx = (int*)d_ws;  // B ints

    find_word_idx<<<B, 256, 0, stream>>>(input, word_idx);
    // G*B waves, 4 waves (256 threads) per block
    scan_and_gather<<<(G * B) / 4, 256, 0, stream>>>(perms, emb, word_idx, out);
}